// Round 4
// baseline (48.934 us; speedup 1.0000x reference)
//
#include <hip/hip_runtime.h>
#include <math.h>

#define NB 1024
#define NC 64
#define NH 64
#define ND 256
#define NHID 256

typedef float f4 __attribute__((ext_vector_type(4)));

// ws layout (floats): [0..255] = v_h, [256] = mask mode (int),
//                     [1024 .. 1024+64*256) = P1 partials (needs ws >= 69632 B)
#define WS_PART_OFF 1024

// mask storage modes: 0 = int32, 1 = byte (bool), 2 = float32
__device__ __forceinline__ bool read_mask(const void* m, int idx, int mode) {
  if (mode == 2) return ((const float*)m)[idx] != 0.0f;
  if (mode == 1) return ((const unsigned char*)m)[idx] != 0;
  return ((const int*)m)[idx] != 0;
}

__device__ __forceinline__ void detect_mode(const unsigned int* mask_cand,
                                            const unsigned int* mask_hist,
                                            int* dst) {
  int sawf = 0; unsigned int big = 0;
  for (int i = 0; i < 32; ++i) {
    unsigned int a = mask_hist[i], b = mask_cand[i];
    if (a == 0x3f800000u || b == 0x3f800000u) sawf = 1;
    if ((a > 1u && a != 0x3f800000u) || (b > 1u && b != 0x3f800000u)) big = 1;
  }
  *dst = sawf ? 2 : (big ? 1 : 0);
}

// ---- P1: 64 blocks x 256 threads: partial v_h over 4 j-rows each ----
__global__ __launch_bounds__(256) void precompute_p1(
    const float* __restrict__ W1, const float* __restrict__ W2,
    float* __restrict__ ws)
{
  const int g = blockIdx.x;
  const int d = threadIdx.x;
  float acc = 0.f;
  #pragma unroll
  for (int jj = 0; jj < 4; ++jj) {
    int j = g * 4 + jj;
    acc = fmaf(W1[(size_t)j * (2 * ND) + ND + d], W2[j], acc);
  }
  ws[WS_PART_OFF + g * ND + d] = acc;
}

// ---- P2: 1 block x 256 threads: reduce partials, detect mask mode ----
__global__ __launch_bounds__(256) void precompute_p2(
    const unsigned int* __restrict__ mask_cand,
    const unsigned int* __restrict__ mask_hist,
    float* __restrict__ ws)
{
  const int d = threadIdx.x;
  float acc = 0.f;
  #pragma unroll 8
  for (int g = 0; g < 64; ++g) acc += ws[WS_PART_OFF + g * ND + d];
  ws[d] = acc;
  if (d == 0) detect_mode(mask_cand, mask_hist, (int*)ws + ND);
}

// ---- fallback single-block precompute (small ws) ----
__global__ __launch_bounds__(1024) void precompute_fallback(
    const float* __restrict__ W1, const float* __restrict__ W2,
    const unsigned int* __restrict__ mask_cand,
    const unsigned int* __restrict__ mask_hist,
    float* __restrict__ ws)
{
  __shared__ float w2_lds[NHID];
  __shared__ float partial[4][ND];
  int t = threadIdx.x;
  if (t < NHID) w2_lds[t] = W2[t];
  __syncthreads();
  int d = t & (ND - 1);
  int g = t >> 8;
  float acc = 0.f;
  #pragma unroll 8
  for (int j = g * 64; j < g * 64 + 64; ++j)
    acc = fmaf(W1[(size_t)j * (2 * ND) + ND + d], w2_lds[j], acc);
  partial[g][d] = acc;
  __syncthreads();
  if (t < ND)
    ws[t] = partial[0][t] + partial[1][t] + partial[2][t] + partial[3][t];
  if (t == 0) detect_mode(mask_cand, mask_hist, (int*)ws + ND);
}

// ---- A: scores + softmax. Pure read stream (67 MB), weights stashed into
// out[b*NC*ND + 0..63] (row c=0 of batch b, overwritten later by B). ----
__global__ __launch_bounds__(512, 8) void score_kernel(
    const float* __restrict__ hist,
    const void* __restrict__ mask_hist_v,
    const float* __restrict__ ws,
    float* __restrict__ wout)
{
  const int b = blockIdx.x;
  const int t = threadIdx.x;
  __shared__ float s_lds[NH];

  const int mode = ((const int*)ws)[ND];
  const float4* hb4 = reinterpret_cast<const float4*>(hist + (size_t)b * NH * ND);
  const float4* vh4p = reinterpret_cast<const float4*>(ws);   // 1KB, L1-hot

  // thread (r = t>>3, cg = t&7): 8 float4 of row r, 128B-coalesced per 8 lanes
  const int r = t >> 3, cg = t & 7;
  float p = 0.f;
  #pragma unroll
  for (int i = 0; i < 8; ++i) {
    float4 x = hb4[r * 64 + i * 8 + cg];
    float4 v = vh4p[i * 8 + cg];
    p = fmaf(x.x, v.x, fmaf(x.y, v.y, fmaf(x.z, v.z, fmaf(x.w, v.w, p))));
  }
  p += __shfl_xor(p, 1); p += __shfl_xor(p, 2); p += __shfl_xor(p, 4);
  if (cg == 0)
    s_lds[r] = read_mask(mask_hist_v, b * NH + r, mode) ? p : -3.0e38f;
  __syncthreads();

  // wave 0: softmax over H=64, write weights
  if (t < 64) {
    float s = s_lds[t];
    float m = s;
    #pragma unroll
    for (int off = 32; off; off >>= 1) m = fmaxf(m, __shfl_xor(m, off));
    float e = expf(s - m);
    float sum = e;
    #pragma unroll
    for (int off = 32; off; off >>= 1) sum += __shfl_xor(sum, off);
    wout[(size_t)b * NC * ND + t] = e / sum;   // normal store -> L2, B reads it
  }
}

// ---- B: uv = sum_h w[h]*hist[h,:], masked broadcast stores.
// hist comes from L3 (resident after A); writes are the HBM stream. ----
__global__ __launch_bounds__(512, 8) void userv_kernel(
    const float* __restrict__ hist,
    const void* __restrict__ mask_cand_v,
    const float* __restrict__ ws,
    float* __restrict__ out)
{
  const int b = blockIdx.x;
  const int t = threadIdx.x;
  const int lane = t & 63;
  const int g = t >> 6;               // wave id 0..7, owns rows g*8..g*8+7

  __shared__ float4 part[8][64];      // 8 KB

  const int mode = ((const int*)ws)[ND];
  const float4* hb4 = reinterpret_cast<const float4*>(hist + (size_t)b * NH * ND);
  float* wsrc = out + (size_t)b * NC * ND;     // weights stashed by A

  // wave-uniform broadcast loads of this wave's 8 weights (before any store)
  float wj[8];
  #pragma unroll
  for (int j = 0; j < 8; ++j) wj[j] = wsrc[g * 8 + j];

  float4 acc = {0.f, 0.f, 0.f, 0.f};
  #pragma unroll
  for (int j = 0; j < 8; ++j) {
    float4 x = hb4[(g * 8 + j) * 64 + lane];   // 1KB contiguous per wave instr
    acc.x = fmaf(wj[j], x.x, acc.x);
    acc.y = fmaf(wj[j], x.y, acc.y);
    acc.z = fmaf(wj[j], x.z, acc.z);
    acc.w = fmaf(wj[j], x.w, acc.w);
  }
  part[g][lane] = acc;
  __syncthreads();

  float4 uv = part[0][lane];
  #pragma unroll
  for (int q = 1; q < 8; ++q) {
    float4 v = part[q][lane];
    uv.x += v.x; uv.y += v.y; uv.z += v.z; uv.w += v.w;
  }

  float4* ob4 = reinterpret_cast<float4*>(out + (size_t)b * NC * ND);
  #pragma unroll
  for (int k = 0; k < 8; ++k) {
    int c = g + k * 8;                // uniform per wave -> 1KB contiguous store
    bool mc = read_mask(mask_cand_v, b * NC + c, mode);
    f4 val = mc ? (f4){uv.x, uv.y, uv.z, uv.w} : (f4){0.f, 0.f, 0.f, 0.f};
    __builtin_nontemporal_store(val, reinterpret_cast<f4*>(&ob4[c * 64 + lane]));
  }
}

extern "C" void kernel_launch(void* const* d_in, const int* in_sizes, int n_in,
                              void* d_out, int out_size, void* d_ws, size_t ws_size,
                              hipStream_t stream) {
  (void)in_sizes; (void)n_in; (void)out_size;
  // inputs: 0 cand [B,C,D] (UNUSED — softmax shift-invariance kills the
  // candidate term), 1 hist [B,H,D], 2 mask_cand, 3 mask_hist,
  // 4 W1 [HID,2D], 5 b1 (unused), 6 W2 [1,HID], 7 b2 (unused)
  const float* hist = (const float*)d_in[1];
  const void*  mask_cand = d_in[2];
  const void*  mask_hist = d_in[3];
  const float* W1 = (const float*)d_in[4];
  const float* W2 = (const float*)d_in[6];
  float* ws = (float*)d_ws;
  float* out = (float*)d_out;

  if (ws_size >= (size_t)(WS_PART_OFF + 64 * ND) * sizeof(float)) {
    precompute_p1<<<64, 256, 0, stream>>>(W1, W2, ws);
    precompute_p2<<<1, 256, 0, stream>>>(
        (const unsigned int*)mask_cand, (const unsigned int*)mask_hist, ws);
  } else {
    precompute_fallback<<<1, 1024, 0, stream>>>(
        W1, W2, (const unsigned int*)mask_cand, (const unsigned int*)mask_hist, ws);
  }
  score_kernel<<<NB, 512, 0, stream>>>(hist, mask_hist, ws, out);
  userv_kernel<<<NB, 512, 0, stream>>>(hist, mask_cand, ws, out);
}

// Round 5
// 47.758 us; speedup vs baseline: 1.0246x; 1.0246x over previous
//
#include <hip/hip_runtime.h>
#include <math.h>

#define NB 1024
#define NC 64
#define NH 64
#define ND 256
#define NHID 256

typedef float f4 __attribute__((ext_vector_type(4)));

// ws layout (floats): [0..255] = v_h, [256] = mask mode (int),
// [1024 .. 1024+64*256)   = P1 partials   (needs ws >= 69,632 B)
// [32768 .. 32768+1024*256) = uv[b][d]    (needs ws >= 1,179,648 B)
#define WS_PART_OFF 1024
#define WS_UV_OFF   32768

// mask storage modes: 0 = int32, 1 = byte (bool), 2 = float32
__device__ __forceinline__ bool read_mask(const void* m, int idx, int mode) {
  if (mode == 2) return ((const float*)m)[idx] != 0.0f;
  if (mode == 1) return ((const unsigned char*)m)[idx] != 0;
  return ((const int*)m)[idx] != 0;
}

__device__ __forceinline__ void detect_mode(const unsigned int* mask_cand,
                                            const unsigned int* mask_hist,
                                            int* dst) {
  int sawf = 0; unsigned int big = 0;
  for (int i = 0; i < 32; ++i) {
    unsigned int a = mask_hist[i], b = mask_cand[i];
    if (a == 0x3f800000u || b == 0x3f800000u) sawf = 1;
    if ((a > 1u && a != 0x3f800000u) || (b > 1u && b != 0x3f800000u)) big = 1;
  }
  *dst = sawf ? 2 : (big ? 1 : 0);
}

// ---- P1: 64 blocks x 256 threads: partial v_h over 4 j-rows each ----
__global__ __launch_bounds__(256) void precompute_p1(
    const float* __restrict__ W1, const float* __restrict__ W2,
    float* __restrict__ ws)
{
  const int g = blockIdx.x;
  const int d = threadIdx.x;
  float acc = 0.f;
  #pragma unroll
  for (int jj = 0; jj < 4; ++jj) {
    int j = g * 4 + jj;
    acc = fmaf(W1[(size_t)j * (2 * ND) + ND + d], W2[j], acc);
  }
  ws[WS_PART_OFF + g * ND + d] = acc;
}

// ---- P2: 1 block x 256 threads: reduce partials, detect mask mode ----
__global__ __launch_bounds__(256) void precompute_p2(
    const unsigned int* __restrict__ mask_cand,
    const unsigned int* __restrict__ mask_hist,
    float* __restrict__ ws)
{
  const int d = threadIdx.x;
  float acc = 0.f;
  #pragma unroll 8
  for (int g = 0; g < 64; ++g) acc += ws[WS_PART_OFF + g * ND + d];
  ws[d] = acc;
  if (d == 0) detect_mode(mask_cand, mask_hist, (int*)ws + ND);
}

// ---- fallback single-block precompute (small ws) ----
__global__ __launch_bounds__(1024) void precompute_fallback(
    const float* __restrict__ W1, const float* __restrict__ W2,
    const unsigned int* __restrict__ mask_cand,
    const unsigned int* __restrict__ mask_hist,
    float* __restrict__ ws)
{
  __shared__ float w2_lds[NHID];
  __shared__ float partial[4][ND];
  int t = threadIdx.x;
  if (t < NHID) w2_lds[t] = W2[t];
  __syncthreads();
  int d = t & (ND - 1);
  int g = t >> 8;
  float acc = 0.f;
  #pragma unroll 8
  for (int j = g * 64; j < g * 64 + 64; ++j)
    acc = fmaf(W1[(size_t)j * (2 * ND) + ND + d], w2_lds[j], acc);
  partial[g][d] = acc;
  __syncthreads();
  if (t < ND)
    ws[t] = partial[0][t] + partial[1][t] + partial[2][t] + partial[3][t];
  if (t == 0) detect_mode(mask_cand, mask_hist, (int*)ws + ND);
}

// ---- A: scores + softmax + uv[b,:]. Read-dominated (67 MB in, 1 MB out). ----
template <int UV_STRIDE>
__global__ __launch_bounds__(512, 8) void score_uv_kernel(
    const float* __restrict__ hist,
    const void* __restrict__ mask_hist_v,
    const float* __restrict__ ws,
    float* __restrict__ uv_dst)
{
  const int b = blockIdx.x;
  const int t = threadIdx.x;
  const int lane = t & 63;
  const int g = t >> 6;               // wave id 0..7

  __shared__ float s_lds[NH];
  __shared__ f4 part[8][64];          // 8 KB

  const int mode = ((const int*)ws)[ND];
  const f4* hb4 = reinterpret_cast<const f4*>(hist + (size_t)b * NH * ND);
  const f4* vh4p = reinterpret_cast<const f4*>(ws);   // 1 KB, L1-hot

  // phase 1: s[r] = dot(hist[b,r,:], v_h); thread (r=t>>3, cg=t&7)
  {
    const int r = t >> 3, cg = t & 7;
    float p = 0.f;
    #pragma unroll
    for (int i = 0; i < 8; ++i) {
      f4 x = hb4[r * 64 + i * 8 + cg];
      f4 v = vh4p[i * 8 + cg];
      p = fmaf(x.x, v.x, fmaf(x.y, v.y, fmaf(x.z, v.z, fmaf(x.w, v.w, p))));
    }
    p += __shfl_xor(p, 1); p += __shfl_xor(p, 2); p += __shfl_xor(p, 4);
    if (cg == 0)
      s_lds[r] = read_mask(mask_hist_v, b * NH + r, mode) ? p : -3.0e38f;
  }
  __syncthreads();

  // phase 2: softmax over H=64, redundant per wave (no extra barrier)
  float wval;
  {
    float s = s_lds[lane];
    float m = s;
    #pragma unroll
    for (int off = 32; off; off >>= 1) m = fmaxf(m, __shfl_xor(m, off));
    float e = expf(s - m);
    float sum = e;
    #pragma unroll
    for (int off = 32; off; off >>= 1) sum += __shfl_xor(sum, off);
    wval = e / sum;
  }

  // phase 3: wave g partial over rows g*8..g*8+7 (re-read, L1/L2-hot)
  {
    f4 acc = {0.f, 0.f, 0.f, 0.f};
    #pragma unroll
    for (int j = 0; j < 8; ++j) {
      float wj = __shfl(wval, g * 8 + j);
      f4 x = hb4[(g * 8 + j) * 64 + lane];
      acc += wj * x;
    }
    part[g][lane] = acc;
  }
  __syncthreads();

  // phase 4: wave 0 reduces the 8 partials, writes uv[b] (1 KB)
  if (t < 64) {
    f4 uv = part[0][t];
    #pragma unroll
    for (int q = 1; q < 8; ++q) uv += part[q][t];
    reinterpret_cast<f4*>(uv_dst + (size_t)b * UV_STRIDE)[t] = uv;
  }
}

// ---- B: pure-write broadcast. 4096 blocks; block (b, q) writes rows
// q*16..q*16+15. Reads 1 KB uv (L2-hot) + 16 mask vals; NT-stores 16 KB. ----
__global__ __launch_bounds__(256) void broadcast_kernel(
    const float* __restrict__ uv_src,
    const void* __restrict__ mask_cand_v,
    const float* __restrict__ ws,
    float* __restrict__ out)
{
  const int bid = blockIdx.x;
  const int b = bid >> 2, q = bid & 3;
  const int t = threadIdx.x, lane = t & 63, g = t >> 6;
  const int mode = ((const int*)ws)[ND];
  const f4 uv = reinterpret_cast<const f4*>(uv_src + (size_t)b * ND)[lane];
  f4* ob4 = reinterpret_cast<f4*>(out + (size_t)b * NC * ND);
  const f4 zero = {0.f, 0.f, 0.f, 0.f};
  #pragma unroll
  for (int j = 0; j < 4; ++j) {
    int c = q * 16 + g * 4 + j;       // uniform per wave -> 1 KB contiguous
    bool mc = read_mask(mask_cand_v, b * NC + c, mode);
    f4 val = mc ? uv : zero;
    __builtin_nontemporal_store(val, &ob4[c * 64 + lane]);
  }
}

// ---- B fallback (uv stashed in out row 0): one block per b ----
__global__ __launch_bounds__(256) void broadcast_stash_kernel(
    const void* __restrict__ mask_cand_v,
    const float* __restrict__ ws,
    float* __restrict__ out)
{
  const int b = blockIdx.x;
  const int t = threadIdx.x, lane = t & 63, g = t >> 6;
  const int mode = ((const int*)ws)[ND];
  f4* ob4 = reinterpret_cast<f4*>(out + (size_t)b * NC * ND);
  const f4 uv = reinterpret_cast<const f4*>(ob4)[lane];   // row 0 stash
  __syncthreads();                                        // all reads before stores
  const f4 zero = {0.f, 0.f, 0.f, 0.f};
  #pragma unroll
  for (int k = 0; k < 16; ++k) {
    int c = g * 16 + k;
    bool mc = read_mask(mask_cand_v, b * NC + c, mode);
    f4 val = mc ? uv : zero;
    __builtin_nontemporal_store(val, &ob4[c * 64 + lane]);
  }
}

extern "C" void kernel_launch(void* const* d_in, const int* in_sizes, int n_in,
                              void* d_out, int out_size, void* d_ws, size_t ws_size,
                              hipStream_t stream) {
  (void)in_sizes; (void)n_in; (void)out_size;
  // inputs: 0 cand [B,C,D] (UNUSED — softmax shift-invariance kills the
  // candidate term), 1 hist [B,H,D], 2 mask_cand, 3 mask_hist,
  // 4 W1 [HID,2D], 5 b1 (unused), 6 W2 [1,HID], 7 b2 (unused)
  const float* hist = (const float*)d_in[1];
  const void*  mask_cand = d_in[2];
  const void*  mask_hist = d_in[3];
  const float* W1 = (const float*)d_in[4];
  const float* W2 = (const float*)d_in[6];
  float* ws = (float*)d_ws;
  float* out = (float*)d_out;

  const bool mid = ws_size >= (size_t)(WS_PART_OFF + 64 * ND) * sizeof(float);
  const bool big = ws_size >= (size_t)(WS_UV_OFF + NB * ND) * sizeof(float);

  if (mid) {
    precompute_p1<<<64, 256, 0, stream>>>(W1, W2, ws);
    precompute_p2<<<1, 256, 0, stream>>>(
        (const unsigned int*)mask_cand, (const unsigned int*)mask_hist, ws);
  } else {
    precompute_fallback<<<1, 1024, 0, stream>>>(
        W1, W2, (const unsigned int*)mask_cand, (const unsigned int*)mask_hist, ws);
  }

  if (big) {
    score_uv_kernel<ND><<<NB, 512, 0, stream>>>(hist, mask_hist, ws, ws + WS_UV_OFF);
    broadcast_kernel<<<NB * 4, 256, 0, stream>>>(ws + WS_UV_OFF, mask_cand, ws, out);
  } else {
    score_uv_kernel<NC * ND><<<NB, 512, 0, stream>>>(hist, mask_hist, ws, out);
    broadcast_stash_kernel<<<NB, 256, 0, stream>>>(mask_cand, ws, out);
  }
}